// Round 3
// baseline (13577.950 us; speedup 1.0000x reference)
//
#include <hip/hip_runtime.h>
#include <hip/hip_bf16.h>
#include <math.h>

// TitanMini forward: B=1024, S=65 (CLS+64), D=512, H=8, DK=64, DFF=1536 (GEGLU), L=10
// Inputs/outputs FLOAT32 (verified r5). Internal: bf16 MFMA GEMMs + fp32 residual.
// r7: GEMM staging via __builtin_amdgcn_global_load_lds width=16 (m97 2-barrier K-loop).
// r8: attn_kernel rewritten with MFMA (QK^T and PV on matrix pipe; was fp32 VALU).
// r9: runtime NCHUNK selection from ws_size (neutral: ws only fits nchunk=4).
// r10: gemm_bt: triple-buffered LDS + raw s_barrier + COUNTED vmcnt(8/4/0) (T4).
//      Loads stay in flight across barriers (2-tile lookahead) instead of the
//      __syncthreads() vmcnt(0) drain. ln_kernel widened to 256thr/4tok.

typedef short short8 __attribute__((ext_vector_type(8)));
typedef float f32x4 __attribute__((ext_vector_type(4)));

#define NLAYER 10
#define DMODEL 512
#define NHEAD 8
#define BATCH 1024
#define SEQ 65

// wT element offsets (ushort)
#define WT_QKV   0L            // 10*1536*512
#define WT_WO    7864320L      // 10*512*512
#define WT_W1    10485760L     // 10*3072*512 (columns interleaved x1/x2)
#define WT_W2    26214400L     // 10*512*1536
#define WT_BQKV  34078720L     // 10*1536
#define WT_BO    34094080L     // 10*512
#define WT_B1    34099200L     // 10*3072 (interleaved)
#define WT_B2    34129920L     // 10*512
#define WT_TOTAL 34135040L

__device__ __forceinline__ float bf2f(ushort u){ return __uint_as_float(((unsigned)u)<<16); }
__device__ __forceinline__ ushort f2bf(float f){
  unsigned u = __float_as_uint(f);
  unsigned r = (u + 0x7fffu + ((u>>16)&1u)) >> 16;
  return (ushort)r;
}
__device__ __forceinline__ float gelu_exact(float x){
  return 0.5f*x*(1.0f+erff(x*0.70710678118654752440f));
}
// async global->LDS, 16B per lane; LDS dest must be wave-uniform base + lane*16
__device__ __forceinline__ void gl16(ushort* lds, const ushort* g){
  __builtin_amdgcn_global_load_lds(
      (const unsigned int __attribute__((address_space(1)))*)g,
      (unsigned int __attribute__((address_space(3)))*)lds,
      16, 0, 0);
}

// ---------------- one-time weight prep: f32 -> transposed bf16 ----------------
__global__ void prep_qkv(const float* __restrict__ Wq, const float* __restrict__ Wk,
                         const float* __restrict__ Wv, ushort* __restrict__ wT)
{
  long idx = (long)blockIdx.x*256 + threadIdx.x;
  if(idx >= 7864320L) return;
  int l = (int)(idx/786432L);
  long r = idx - (long)l*786432L;
  int n = (int)(r>>9), k = (int)(r&511);
  float v;
  if(n<512)       v = Wq[(long)l*262144 + (long)k*512 + n];
  else if(n<1024) v = Wk[(long)l*262144 + (long)k*512 + (n-512)];
  else            v = Wv[(long)l*262144 + (long)k*512 + (n-1024)];
  wT[WT_QKV + idx] = f2bf(v);
}
__global__ void prep_wo(const float* __restrict__ Wo, ushort* __restrict__ wT)
{
  long idx = (long)blockIdx.x*256 + threadIdx.x;
  if(idx >= 2621440L) return;
  int l = (int)(idx/262144L);
  long r = idx - (long)l*262144L;
  int n = (int)(r>>9), k = (int)(r&511);
  wT[WT_WO + idx] = f2bf(Wo[(long)l*262144 + (long)k*512 + n]);
}
__global__ void prep_w1(const float* __restrict__ W1, ushort* __restrict__ wT)
{
  long idx = (long)blockIdx.x*256 + threadIdx.x;
  if(idx >= 15728640L) return;
  int l = (int)(idx/1572864L);
  long r = idx - (long)l*1572864L;
  int n = (int)(r>>9), k = (int)(r&511);
  int j = n>>1;
  int src = (n&1) ? 1536+j : j;       // even n -> x1 col j, odd n -> x2 col j
  wT[WT_W1 + idx] = f2bf(W1[(long)l*1572864 + (long)k*3072 + src]);
}
__global__ void prep_w2(const float* __restrict__ W2, ushort* __restrict__ wT)
{
  long idx = (long)blockIdx.x*256 + threadIdx.x;
  if(idx >= 7864320L) return;
  int l = (int)(idx/786432L);
  long r = idx - (long)l*786432L;
  int n = (int)(r/1536), k = (int)(r - (long)n*1536);
  wT[WT_W2 + idx] = f2bf(W2[(long)l*786432 + (long)k*512 + n]);
}
__global__ void prep_bias(const float* __restrict__ bq, const float* __restrict__ bk,
                          const float* __restrict__ bv, const float* __restrict__ bo,
                          const float* __restrict__ b1, const float* __restrict__ b2,
                          ushort* __restrict__ wT)
{
  int idx = blockIdx.x*256 + threadIdx.x;
  if(idx >= 56320) return;
  long o = WT_BQKV + idx;
  float v;
  if(o < WT_BO){
    int i = idx;                 // bqkv: l*1536 + n
    int l = i/1536, n = i - l*1536;
    if(n<512) v=bq[l*512+n]; else if(n<1024) v=bk[l*512+n-512]; else v=bv[l*512+n-1024];
  } else if(o < WT_B1){
    int i = (int)(o - WT_BO);
    v = bo[i];
  } else if(o < WT_B2){
    int i = (int)(o - WT_B1);    // b1 interleaved: l*3072 + n
    int l = i/3072, n = i - l*3072;
    int j=n>>1; int src=(n&1)?1536+j:j;
    v = b1[l*3072+src];
  } else {
    int i = (int)(o - WT_B2);
    v = b2[i];
  }
  wT[o] = f2bf(v);
}

// ---------------- embedding + positional tables -> t (fp32), chunk-local ----------------
__global__ __launch_bounds__(64) void embed_kernel(
    const float* __restrict__ x, const float* __restrict__ emb_W,
    const float* __restrict__ emb_b, const float* __restrict__ cls,
    const float* __restrict__ abs_pos, const float* __restrict__ file_tab,
    const float* __restrict__ rank_tab, const float* __restrict__ diag_tab,
    const float* __restrict__ anti_tab, float* __restrict__ t, long xoff)
{
  long tok = blockIdx.x;
  int lane = threadIdx.x;
  long b = tok/SEQ;
  int s = (int)(tok - b*SEQ);
  float* out = t + tok*DMODEL;
  if(s==0){
    #pragma unroll
    for(int j=0;j<8;j++){ int d=lane*8+j; out[d]=cls[d]; }
    return;
  }
  int p = s-1;
  int f = p&7, r = p>>3;
  int dg = r+f, ad = r-f+7;
  float xv[16];
  #pragma unroll
  for(int k=0;k<16;k++) xv[k]=x[xoff + (b*64+p)*16+k];
  #pragma unroll
  for(int j=0;j<8;j++){
    int d = lane*8+j;
    float acc = emb_b[d] + abs_pos[p*512+d] + file_tab[f*512+d]
              + rank_tab[r*512+d] + diag_tab[dg*512+d] + anti_tab[ad*512+d];
    #pragma unroll
    for(int k=0;k<16;k++) acc += xv[k]*emb_W[k*512+d];
    out[d]=acc;
  }
}

// ---------------- LayerNorm: t(fp32) -> h(bf16). 4 tokens/block (1/wave) ----------------
__global__ __launch_bounds__(256) void ln_kernel(const float* __restrict__ t, ushort* __restrict__ h,
                                                 const float* __restrict__ g, const float* __restrict__ b,
                                                 long goff)
{
  long tok = (long)blockIdx.x*4 + (threadIdx.x>>6);
  int lane = threadIdx.x&63;
  const float* row = t + tok*DMODEL;
  float4 v0 = *reinterpret_cast<const float4*>(row + lane*8);
  float4 v1 = *reinterpret_cast<const float4*>(row + lane*8 + 4);
  float x[8] = {v0.x,v0.y,v0.z,v0.w,v1.x,v1.y,v1.z,v1.w};
  float s=0.f, ss=0.f;
  #pragma unroll
  for(int j=0;j<8;j++){ s+=x[j]; ss+=x[j]*x[j]; }
  #pragma unroll
  for(int off=32;off>=1;off>>=1){ s+=__shfl_down(s,off); ss+=__shfl_down(ss,off); }
  s=__shfl(s,0); ss=__shfl(ss,0);
  float mean = s*(1.0f/512.0f);
  float var  = ss*(1.0f/512.0f) - mean*mean;
  float rs = rsqrtf(fmaxf(var,0.0f) + 1e-5f);
  #pragma unroll
  for(int j=0;j<8;j++){
    int d=lane*8+j;
    h[tok*DMODEL+d] = f2bf((x[j]-mean)*rs*g[goff+d] + b[goff+d]);
  }
}

// ---------------- GEMM: C[M][N] = A[M][lda] @ BT[N][K]^T + bias(bf16) ----------------
// r10 structure: triple-buffered LDS (48KB), 2-tile prefetch lookahead, raw s_barrier,
// COUNTED vmcnt (8 mid-loop / 4 / 0 last) so staging loads stay in flight across
// barriers (T4). Fragment math, staging map, and epilogues unchanged from r7.
// EPI 0: Cb = acc+bias (bf16)
// EPI 1: Cf += acc+bias (fp32 residual)
// EPI 2: GEGLU — BT columns interleaved (x1,x2); even lanes write gelu(x1)*x2 at col n>>1
template<int EPI>
__global__ __launch_bounds__(256,2) void gemm_bt(
    const ushort* __restrict__ A, long lda,
    const ushort* __restrict__ BT,
    const ushort* __restrict__ bias,
    ushort* __restrict__ Cb, float* __restrict__ Cf,
    long ldc, int K)
{
  __shared__ __align__(16) ushort LA[3][128*32];   // 3 x 8KB
  __shared__ __align__(16) ushort LB[3][128*32];   // 3 x 8KB  (total 48KB)
  const int tid = threadIdx.x;
  const int w = tid>>6, lane = tid&63, q = lane>>4, lr = lane&15;
  const int wm = (w>>1)*64, wn = (w&1)*64;
  const long mBase = (long)blockIdx.y*128, nBase = (long)blockIdx.x*128;

  f32x4 acc[4][4];
  #pragma unroll
  for(int i=0;i<4;i++)
    #pragma unroll
    for(int j=0;j<4;j++) acc[i][j]=(f32x4)(0.0f);

  const int idx0=tid, idx1=tid+256;
  const int ar0=idx0>>2, ac0=(idx0&3)*8;
  const int ar1=idx1>>2, ac1=(idx1&3)*8;

  const ushort* gA0 = A  + (mBase+ar0)*lda     + ac0;
  const ushort* gA1 = A  + (mBase+ar1)*lda     + ac1;
  const ushort* gB0 = BT + (nBase+ar0)*(long)K + ac0;
  const ushort* gB1 = BT + (nBase+ar1)*(long)K + ac1;

  const int NT = K>>5;                       // 32-wide K-tiles (>=16 for all our shapes)

  // stage K-tile kt into buffer b: 4 async 16B/lane loads (order defines vmcnt count)
  #define STAGE(bf,kt) do{ int _k0=(kt)<<5;                 \
      gl16(&LA[bf][idx0*8], gA0 + _k0);                     \
      gl16(&LA[bf][idx1*8], gA1 + _k0);                     \
      gl16(&LB[bf][idx0*8], gB0 + _k0);                     \
      gl16(&LB[bf][idx1*8], gB1 + _k0); }while(0)

  STAGE(0,0);
  STAGE(1,1);

  int c = 0;                                 // buffer holding tile t
  for(int t=0;t<NT;t++){
    if(t+2<NT){
      int nb = c+2; if(nb>=3) nb-=3;         // buffer of tile t-1, free since last barrier
      STAGE(nb, t+2);
      // outstanding: tiles t(4) t+1(4) t+2(4) -> wait to 8: tile t landed, 8 in flight
      asm volatile("s_waitcnt vmcnt(8)" ::: "memory");
    } else if(t+1<NT){
      asm volatile("s_waitcnt vmcnt(4)" ::: "memory");   // tile t landed, t+1 in flight
    } else {
      asm volatile("s_waitcnt vmcnt(0)" ::: "memory");   // final tile
    }
    __builtin_amdgcn_s_barrier();            // all waves' tile-t loads landed -> LDS valid
    __builtin_amdgcn_sched_barrier(0);

    const ushort* As = LA[c];
    const ushort* Bs = LB[c];
    short8 af[4], bfr[4];
    #pragma unroll
    for(int mt=0;mt<4;mt++) af[mt]=*reinterpret_cast<const short8*>(As + (wm+mt*16+lr)*32 + q*8);
    #pragma unroll
    for(int nt=0;nt<4;nt++) bfr[nt]=*reinterpret_cast<const short8*>(Bs + (wn+nt*16+lr)*32 + q*8);
    #pragma unroll
    for(int mt=0;mt<4;mt++)
      #pragma unroll
      for(int nt=0;nt<4;nt++)
        acc[mt][nt]=__builtin_amdgcn_mfma_f32_16x16x32_bf16(af[mt],bfr[nt],acc[mt][nt],0,0,0);

    asm volatile("" ::: "memory");
    __builtin_amdgcn_s_barrier();            // reads of buf c done -> next iter may overwrite
    __builtin_amdgcn_sched_barrier(0);
    c = c+1; if(c>=3) c-=3;
  }
  #undef STAGE

  #pragma unroll
  for(int nt=0;nt<4;nt++){
    long n = nBase+wn+nt*16+lr;
    float bv = bf2f(bias[n]);
    #pragma unroll
    for(int mt=0;mt<4;mt++){
      #pragma unroll
      for(int r=0;r<4;r++){
        long m = mBase+wm+mt*16+q*4+r;
        float v = acc[mt][nt][r]+bv;
        if constexpr (EPI==0){
          Cb[m*ldc+n]=f2bf(v);
        } else if constexpr (EPI==1){
          Cf[m*ldc+n]+=v;
        } else {
          float partner = __shfl_xor(v,1);
          if(!(lane&1)) Cb[m*ldc + (n>>1)] = f2bf(gelu_exact(v)*partner);
        }
      }
    }
  }
}

// ---------------- fused attention per (b,h): MFMA QK^T + softmax + MFMA PV ----------------
// Q,K natural [s][64] bf16 in LDS (A-frag / BT-frag layouts match gemm_bt's m89-verified
// mapping: row=lane&15, k=(lane>>4)*8). V staged transposed Vt[d][s] for the PV B-operand.
// Pad 65->80 rows (5 M/N tiles); PV K padded to 96 (3 k-steps) with P/Vt pad cols zeroed.
// LDS strides 72/81/104 break the 128B-row bank conflict (G4).
__global__ __launch_bounds__(256) void attn_kernel(const ushort* __restrict__ qkv,
                                                   const float* __restrict__ rel_bias,
                                                   ushort* __restrict__ ctx, int layer)
{
  int bh = blockIdx.x;
  long b = bh>>3;
  int h = bh&7;
  __shared__ __align__(16) ushort Qb[80*72];    // 11520 B
  __shared__ __align__(16) ushort Kb[80*72];    // 11520 B
  __shared__ __align__(16) ushort Vt[64*104];   // 13312 B  Vt[d][s]
  __shared__ __align__(16) float  S [80*81];    // 25920 B
  __shared__ __align__(16) ushort Pb[80*104];   // 16640 B
  __shared__ float relb[225];
  const long tokBase = b*SEQ;
  const int tid = threadIdx.x;
  const int w = tid>>6, lane = tid&63, q = lane>>4, lr = lane&15;

  // ---- stage Q,K,V (V transposed), zero Vt pad cols, load bias table ----
  for(int idx=tid; idx<SEQ*8; idx+=256){           // 520 rows-of-8
    int s = idx>>3, c8 = (idx&7)<<3;
    long base = (tokBase+s)*1536 + h*64 + c8;
    *reinterpret_cast<short8*>(&Qb[s*72 + c8]) = *reinterpret_cast<const short8*>(&qkv[base]);
    *reinterpret_cast<short8*>(&Kb[s*72 + c8]) = *reinterpret_cast<const short8*>(&qkv[base+512]);
    short8 v = *reinterpret_cast<const short8*>(&qkv[base+1024]);
    #pragma unroll
    for(int j=0;j<8;j++) Vt[(c8+j)*104 + s] = (ushort)v[j];
  }
  for(int idx=tid; idx<64*32; idx+=256){           // zero Vt[d][65..96]
    int d = idx>>5, s = 65+(idx&31);
    Vt[d*104 + s] = 0;
  }
  if(tid<225) relb[tid] = rel_bias[((long)layer*225 + tid)*8 + h];
  __syncthreads();

  // ---- scores: S[qi][ki] = (Q @ K^T) * 0.125  via 5x5 tiles of 16x16x32 ----
  for(int tt=w; tt<25; tt+=4){
    int mt = tt/5, nt = tt - mt*5;
    f32x4 acc = (f32x4)(0.0f);
    #pragma unroll
    for(int ks=0;ks<2;ks++){
      short8 af = *reinterpret_cast<const short8*>(&Qb[(mt*16+lr)*72 + ks*32 + q*8]);
      short8 bf = *reinterpret_cast<const short8*>(&Kb[(nt*16+lr)*72 + ks*32 + q*8]);
      acc = __builtin_amdgcn_mfma_f32_16x16x32_bf16(af, bf, acc, 0,0,0);
    }
    int col = nt*16 + lr;
    #pragma unroll
    for(int r=0;r<4;r++)
      S[(mt*16 + q*4 + r)*81 + col] = acc[r]*0.125f;
  }
  __syncthreads();

  // ---- softmax per row (wave-parallel rows; adds rel-pos bias) -> Pb bf16 ----
  if(tid < SEQ){
    int qi = tid;
    float* srow = S + qi*81;
    int pq = qi-1;
    float mx = -1e30f;
    for(int k=0;k<SEQ;k++){
      float s = srow[k];
      if(qi>0 && k>0){
        int pk = k-1;
        int ridx = (pq>>3)-(pk>>3)+7, fidx = (pq&7)-(pk&7)+7;
        s += relb[ridx*15+fidx];
      }
      srow[k] = s;
      mx = fmaxf(mx, s);
    }
    float sum = 0.f;
    for(int k=0;k<SEQ;k++){ float e = __expf(srow[k]-mx); srow[k]=e; sum+=e; }
    float inv = 1.0f/sum;
    ushort* prow = Pb + qi*104;
    for(int k=0;k<SEQ;k++) prow[k] = f2bf(srow[k]*inv);
    for(int k=SEQ;k<96;k++) prow[k] = 0;           // zero pad -> PV k-steps safe
  }
  __syncthreads();

  // ---- PV: ctx[qi][d] = P @ V  via 5x4 tiles, K=96 (3 k-steps) ----
  for(int tt=w; tt<20; tt+=4){
    int mt = tt>>2, nt = tt&3;
    f32x4 acc = (f32x4)(0.0f);
    #pragma unroll
    for(int ks=0;ks<3;ks++){
      short8 af = *reinterpret_cast<const short8*>(&Pb[(mt*16+lr)*104 + ks*32 + q*8]);
      short8 bf = *reinterpret_cast<const short8*>(&Vt[(nt*16+lr)*104 + ks*32 + q*8]);
      acc = __builtin_amdgcn_mfma_f32_16x16x32_bf16(af, bf, acc, 0,0,0);
    }
    int col = nt*16 + lr;
    #pragma unroll
    for(int r=0;r<4;r++){
      int row = mt*16 + q*4 + r;
      if(row < SEQ)
        ctx[(tokBase+row)*512 + h*64 + col] = f2bf(acc[r]);
    }
  }
}

// ---------------- policy head: out[(b0+bl)*4608 + p*72+j] (float) ----------------
__global__ __launch_bounds__(128) void policy_kernel(const ushort* __restrict__ h,
                                                     const float* __restrict__ pol_W,
                                                     const float* __restrict__ pol_b,
                                                     float* __restrict__ out, long b0)
{
  int bp = blockIdx.x;           // bl*64 + p
  long bl = bp>>6;
  int p = bp&63;
  const ushort* hrow = h + (bl*SEQ + 1 + p)*DMODEL;
  __shared__ float hl[DMODEL];
  for(int d=threadIdx.x; d<DMODEL; d+=128) hl[d]=bf2f(hrow[d]);
  __syncthreads();
  int j = threadIdx.x;
  if(j<72){
    float acc = pol_b[j];
    for(int k=0;k<DMODEL;k++) acc += hl[k]*pol_W[k*72+j];
    out[(b0+bl)*4608 + (long)p*72 + j] = acc;
  }
}

// ---------------- value head MLP on CLS token (float out) ----------------
__global__ __launch_bounds__(256) void value_kernel(const ushort* __restrict__ h,
                                                    const float* __restrict__ v1_W, const float* __restrict__ v1_b,
                                                    const float* __restrict__ v2_W, const float* __restrict__ v2_b,
                                                    const float* __restrict__ v3_W, const float* __restrict__ v3_b,
                                                    float* __restrict__ out, long b0)
{
  long bl = blockIdx.x;
  int tid = threadIdx.x;
  __shared__ float vh[512], a1[256], a2[128];
  const ushort* hrow = h + bl*SEQ*DMODEL;   // CLS token
  for(int d=tid; d<512; d+=256) vh[d]=bf2f(hrow[d]);
  __syncthreads();
  {
    float acc = v1_b[tid];
    for(int k=0;k<512;k++) acc += vh[k]*v1_W[k*256+tid];
    a1[tid]=gelu_exact(acc);
  }
  __syncthreads();
  if(tid<128){
    float acc = v2_b[tid];
    for(int k=0;k<256;k++) acc += a1[k]*v2_W[k*128+tid];
    a2[tid]=gelu_exact(acc);
  }
  __syncthreads();
  if(tid==0){
    float acc = v3_b[0];
    for(int k=0;k<128;k++) acc += a2[k]*v3_W[k];
    out[(long)BATCH*4608 + b0 + bl] = tanhf(acc);
  }
}

extern "C" void kernel_launch(void* const* d_in, const int* in_sizes, int n_in,
                              void* d_out, int out_size, void* d_ws, size_t ws_size,
                              hipStream_t stream)
{
  const float* x        = (const float*)d_in[0];
  const float* emb_W    = (const float*)d_in[1];
  const float* emb_b    = (const float*)d_in[2];
  const float* cls      = (const float*)d_in[3];
  const float* abs_pos  = (const float*)d_in[4];
  const float* file_tab = (const float*)d_in[5];
  const float* rank_tab = (const float*)d_in[6];
  const float* diag_tab = (const float*)d_in[7];
  const float* anti_tab = (const float*)d_in[8];
  const float* rel_bias = (const float*)d_in[9];
  const float* Wq  = (const float*)d_in[10];
  const float* bq  = (const float*)d_in[11];
  const float* Wk  = (const float*)d_in[12];
  const float* bk  = (const float*)d_in[13];
  const float* Wv  = (const float*)d_in[14];
  const float* bv  = (const float*)d_in[15];
  const float* Wo  = (const float*)d_in[16];
  const float* bo  = (const float*)d_in[17];
  const float* ln1_g = (const float*)d_in[18];
  const float* ln1_b = (const float*)d_in[19];
  const float* ln2_g = (const float*)d_in[20];
  const float* ln2_b = (const float*)d_in[21];
  const float* W1  = (const float*)d_in[22];
  const float* b1  = (const float*)d_in[23];
  const float* W2  = (const float*)d_in[24];
  const float* b2  = (const float*)d_in[25];
  const float* fln_g = (const float*)d_in[26];
  const float* fln_b = (const float*)d_in[27];
  const float* pol_W = (const float*)d_in[28];
  const float* pol_b = (const float*)d_in[29];
  const float* v1_W  = (const float*)d_in[30];
  const float* v1_b  = (const float*)d_in[31];
  const float* v2_W  = (const float*)d_in[32];
  const float* v2_b  = (const float*)d_in[33];
  const float* v3_W  = (const float*)d_in[34];
  const float* v3_b  = (const float*)d_in[35];
  float* out = (float*)d_out;

  // --- runtime chunk selection: pick largest chunk that fits ws_size ---
  int nchunk = 4;
  if(ws_size >= (size_t)477214720) nchunk = 1;
  else if(ws_size >= (size_t)272742400) nchunk = 2;
  const int bch = BATCH / nchunk;          // batches per chunk
  const long mch = (long)bch * SEQ;        // tokens per chunk (divisible by 128/4)

  char* ws = (char*)d_ws;
  float*  t    = (float*)ws;  ws += (size_t)mch*DMODEL*4;
  ushort* h    = (ushort*)ws; ws += (size_t)mch*DMODEL*2;   // also ctx
  ushort* buf1 = (ushort*)ws; ws += (size_t)mch*1536*2;     // qkv / geglu out
  ushort* wT   = (ushort*)ws; ws += (size_t)WT_TOTAL*2;
  (void)ws_size; (void)in_sizes; (void)n_in; (void)out_size;

  // --- one-time weight prep ---
  prep_qkv<<<(7864320+255)/256,256,0,stream>>>(Wq,Wk,Wv,wT);
  prep_wo <<<(2621440+255)/256,256,0,stream>>>(Wo,wT);
  prep_w1 <<<(15728640+255)/256,256,0,stream>>>(W1,wT);
  prep_w2 <<<(7864320+255)/256,256,0,stream>>>(W2,wT);
  prep_bias<<<(56320+255)/256,256,0,stream>>>(bq,bk,bv,bo,b1,b2,wT);

  // --- per-chunk full network ---
  const int gy = (int)(mch/128);           // GEMM grid rows
  const int lng = (int)(mch/4);            // LN grid (4 tokens/block)
  for(int c=0;c<nchunk;c++){
    long b0 = (long)c*bch;
    embed_kernel<<<(int)mch,64,0,stream>>>(x, emb_W, emb_b, cls, abs_pos,
                                      file_tab, rank_tab, diag_tab, anti_tab, t, b0*64*16);
    for(int l=0;l<NLAYER;l++){
      ln_kernel<<<lng,256,0,stream>>>(t, h, ln1_g, ln1_b, l*512);
      gemm_bt<0><<<dim3(12,gy),256,0,stream>>>(h, 512, wT+WT_QKV+(long)l*786432,
                                                wT+WT_BQKV+l*1536, buf1, nullptr, 1536, 512);
      attn_kernel<<<bch*NHEAD,256,0,stream>>>(buf1, rel_bias, h, l);   // ctx -> h
      gemm_bt<1><<<dim3(4,gy),256,0,stream>>>(h, 512, wT+WT_WO+(long)l*262144,
                                               wT+WT_BO+l*512, nullptr, t, 512, 512);
      ln_kernel<<<lng,256,0,stream>>>(t, h, ln2_g, ln2_b, l*512);
      gemm_bt<2><<<dim3(24,gy),256,0,stream>>>(h, 512, wT+WT_W1+(long)l*1572864,
                                                wT+WT_B1+l*3072, buf1, nullptr, 1536, 512);
      gemm_bt<1><<<dim3(4,gy),256,0,stream>>>(buf1, 1536, wT+WT_W2+(long)l*786432,
                                               wT+WT_B2+l*512, nullptr, t, 512, 1536);
    }
    ln_kernel<<<lng,256,0,stream>>>(t, h, fln_g, fln_b, 0);
    policy_kernel<<<bch*64,128,0,stream>>>(h, pol_W, pol_b, out, b0);
    value_kernel<<<bch,256,0,stream>>>(h, v1_W, v1_b, v2_W, v2_b, v3_W, v3_b, out, b0);
  }
}

// Round 4
// 12385.555 us; speedup vs baseline: 1.0963x; 1.0963x over previous
//
#include <hip/hip_runtime.h>
#include <hip/hip_bf16.h>
#include <math.h>

// TitanMini forward: B=1024, S=65 (CLS+64), D=512, H=8, DK=64, DFF=1536 (GEGLU), L=10
// Inputs/outputs FLOAT32 (verified r5). Internal: bf16 MFMA GEMMs + fp32 residual.
// r7: GEMM staging via __builtin_amdgcn_global_load_lds width=16 (m97 2-barrier K-loop).
// r8: attn_kernel rewritten with MFMA (QK^T and PV on matrix pipe; was fp32 VALU).
// r9: runtime NCHUNK selection from ws_size (neutral: ws only fits nchunk=4).
// r10: counted-vmcnt triple-buffer REGRESSED (+423us; T4 needs 8-phase gate) -> REVERTED.
// r11: gemm_bt back to r9's verified 2-barrier loop. Policy head -> MFMA GEMM (EPI=3,
//      pol_W zero-padded to 128 cols). attn softmax wave-parallelized (4-lane groups).

typedef short short8 __attribute__((ext_vector_type(8)));
typedef float f32x4 __attribute__((ext_vector_type(4)));

#define NLAYER 10
#define DMODEL 512
#define NHEAD 8
#define BATCH 1024
#define SEQ 65

// wT element offsets (ushort)
#define WT_QKV   0L            // 10*1536*512
#define WT_WO    7864320L      // 10*512*512
#define WT_W1    10485760L     // 10*3072*512 (columns interleaved x1/x2)
#define WT_W2    26214400L     // 10*512*1536
#define WT_BQKV  34078720L     // 10*1536
#define WT_BO    34094080L     // 10*512
#define WT_B1    34099200L     // 10*3072 (interleaved)
#define WT_B2    34129920L     // 10*512
#define WT_POL   34135040L     // 128*512 (pol_W^T, zero-padded rows 72..127)
#define WT_BPOL  34200576L     // 128
#define WT_TOTAL 34200704L

__device__ __forceinline__ float bf2f(ushort u){ return __uint_as_float(((unsigned)u)<<16); }
__device__ __forceinline__ ushort f2bf(float f){
  unsigned u = __float_as_uint(f);
  unsigned r = (u + 0x7fffu + ((u>>16)&1u)) >> 16;
  return (ushort)r;
}
__device__ __forceinline__ float gelu_exact(float x){
  return 0.5f*x*(1.0f+erff(x*0.70710678118654752440f));
}
// async global->LDS, 16B per lane; LDS dest must be wave-uniform base + lane*16
__device__ __forceinline__ void gl16(ushort* lds, const ushort* g){
  __builtin_amdgcn_global_load_lds(
      (const unsigned int __attribute__((address_space(1)))*)g,
      (unsigned int __attribute__((address_space(3)))*)lds,
      16, 0, 0);
}

// ---------------- one-time weight prep: f32 -> transposed bf16 ----------------
__global__ void prep_qkv(const float* __restrict__ Wq, const float* __restrict__ Wk,
                         const float* __restrict__ Wv, ushort* __restrict__ wT)
{
  long idx = (long)blockIdx.x*256 + threadIdx.x;
  if(idx >= 7864320L) return;
  int l = (int)(idx/786432L);
  long r = idx - (long)l*786432L;
  int n = (int)(r>>9), k = (int)(r&511);
  float v;
  if(n<512)       v = Wq[(long)l*262144 + (long)k*512 + n];
  else if(n<1024) v = Wk[(long)l*262144 + (long)k*512 + (n-512)];
  else            v = Wv[(long)l*262144 + (long)k*512 + (n-1024)];
  wT[WT_QKV + idx] = f2bf(v);
}
__global__ void prep_wo(const float* __restrict__ Wo, ushort* __restrict__ wT)
{
  long idx = (long)blockIdx.x*256 + threadIdx.x;
  if(idx >= 2621440L) return;
  int l = (int)(idx/262144L);
  long r = idx - (long)l*262144L;
  int n = (int)(r>>9), k = (int)(r&511);
  wT[WT_WO + idx] = f2bf(Wo[(long)l*262144 + (long)k*512 + n]);
}
__global__ void prep_w1(const float* __restrict__ W1, ushort* __restrict__ wT)
{
  long idx = (long)blockIdx.x*256 + threadIdx.x;
  if(idx >= 15728640L) return;
  int l = (int)(idx/1572864L);
  long r = idx - (long)l*1572864L;
  int n = (int)(r>>9), k = (int)(r&511);
  int j = n>>1;
  int src = (n&1) ? 1536+j : j;       // even n -> x1 col j, odd n -> x2 col j
  wT[WT_W1 + idx] = f2bf(W1[(long)l*1572864 + (long)k*3072 + src]);
}
__global__ void prep_w2(const float* __restrict__ W2, ushort* __restrict__ wT)
{
  long idx = (long)blockIdx.x*256 + threadIdx.x;
  if(idx >= 7864320L) return;
  int l = (int)(idx/786432L);
  long r = idx - (long)l*786432L;
  int n = (int)(r/1536), k = (int)(r - (long)n*1536);
  wT[WT_W2 + idx] = f2bf(W2[(long)l*786432 + (long)k*512 + n]);
}
__global__ void prep_bias(const float* __restrict__ bq, const float* __restrict__ bk,
                          const float* __restrict__ bv, const float* __restrict__ bo,
                          const float* __restrict__ b1, const float* __restrict__ b2,
                          ushort* __restrict__ wT)
{
  int idx = blockIdx.x*256 + threadIdx.x;
  if(idx >= 56320) return;
  long o = WT_BQKV + idx;
  float v;
  if(o < WT_BO){
    int i = idx;                 // bqkv: l*1536 + n
    int l = i/1536, n = i - l*1536;
    if(n<512) v=bq[l*512+n]; else if(n<1024) v=bk[l*512+n-512]; else v=bv[l*512+n-1024];
  } else if(o < WT_B1){
    int i = (int)(o - WT_BO);
    v = bo[i];
  } else if(o < WT_B2){
    int i = (int)(o - WT_B1);    // b1 interleaved: l*3072 + n
    int l = i/3072, n = i - l*3072;
    int j=n>>1; int src=(n&1)?1536+j:j;
    v = b1[l*3072+src];
  } else {
    int i = (int)(o - WT_B2);
    v = b2[i];
  }
  wT[o] = f2bf(v);
}
__global__ void prep_pol(const float* __restrict__ pol_W, const float* __restrict__ pol_b,
                         ushort* __restrict__ wT)
{
  int idx = blockIdx.x*256 + threadIdx.x;
  if(idx >= 65536+128) return;
  if(idx < 65536){
    int n = idx>>9, k = idx&511;
    wT[WT_POL + idx] = f2bf(n<72 ? pol_W[k*72+n] : 0.0f);
  } else {
    int n = idx - 65536;
    wT[WT_BPOL + n] = f2bf(n<72 ? pol_b[n] : 0.0f);
  }
}

// ---------------- embedding + positional tables -> t (fp32), chunk-local ----------------
__global__ __launch_bounds__(64) void embed_kernel(
    const float* __restrict__ x, const float* __restrict__ emb_W,
    const float* __restrict__ emb_b, const float* __restrict__ cls,
    const float* __restrict__ abs_pos, const float* __restrict__ file_tab,
    const float* __restrict__ rank_tab, const float* __restrict__ diag_tab,
    const float* __restrict__ anti_tab, float* __restrict__ t, long xoff)
{
  long tok = blockIdx.x;
  int lane = threadIdx.x;
  long b = tok/SEQ;
  int s = (int)(tok - b*SEQ);
  float* out = t + tok*DMODEL;
  if(s==0){
    #pragma unroll
    for(int j=0;j<8;j++){ int d=lane*8+j; out[d]=cls[d]; }
    return;
  }
  int p = s-1;
  int f = p&7, r = p>>3;
  int dg = r+f, ad = r-f+7;
  float xv[16];
  #pragma unroll
  for(int k=0;k<16;k++) xv[k]=x[xoff + (b*64+p)*16+k];
  #pragma unroll
  for(int j=0;j<8;j++){
    int d = lane*8+j;
    float acc = emb_b[d] + abs_pos[p*512+d] + file_tab[f*512+d]
              + rank_tab[r*512+d] + diag_tab[dg*512+d] + anti_tab[ad*512+d];
    #pragma unroll
    for(int k=0;k<16;k++) acc += xv[k]*emb_W[k*512+d];
    out[d]=acc;
  }
}

// ---------------- LayerNorm: t(fp32) -> h(bf16). 4 tokens/block (1/wave) ----------------
__global__ __launch_bounds__(256) void ln_kernel(const float* __restrict__ t, ushort* __restrict__ h,
                                                 const float* __restrict__ g, const float* __restrict__ b,
                                                 long goff)
{
  long tok = (long)blockIdx.x*4 + (threadIdx.x>>6);
  int lane = threadIdx.x&63;
  const float* row = t + tok*DMODEL;
  float4 v0 = *reinterpret_cast<const float4*>(row + lane*8);
  float4 v1 = *reinterpret_cast<const float4*>(row + lane*8 + 4);
  float x[8] = {v0.x,v0.y,v0.z,v0.w,v1.x,v1.y,v1.z,v1.w};
  float s=0.f, ss=0.f;
  #pragma unroll
  for(int j=0;j<8;j++){ s+=x[j]; ss+=x[j]*x[j]; }
  #pragma unroll
  for(int off=32;off>=1;off>>=1){ s+=__shfl_down(s,off); ss+=__shfl_down(ss,off); }
  s=__shfl(s,0); ss=__shfl(ss,0);
  float mean = s*(1.0f/512.0f);
  float var  = ss*(1.0f/512.0f) - mean*mean;
  float rs = rsqrtf(fmaxf(var,0.0f) + 1e-5f);
  #pragma unroll
  for(int j=0;j<8;j++){
    int d=lane*8+j;
    h[tok*DMODEL+d] = f2bf((x[j]-mean)*rs*g[goff+d] + b[goff+d]);
  }
}

// ---------------- GEMM: C[M][N] = A[M][lda] @ BT[N][K]^T + bias(bf16) ----------------
// Staging: global_load_lds width=16 (async, m97 2-barrier K-loop). [r11: reverted to
// the verified r9 structure — counted-vmcnt graft regressed without the 8-phase gate.]
// EPI 0: Cb = acc+bias (bf16)
// EPI 1: Cf += acc+bias (fp32 residual)
// EPI 2: GEGLU — BT columns interleaved (x1,x2); even lanes write gelu(x1)*x2 at col n>>1
// EPI 3: policy — m -> (bl=m/65, p=m%65-1); write fp32 Cf[bl*4608+p*72+n] for p>=0,n<72
template<int EPI>
__global__ __launch_bounds__(256,2) void gemm_bt(
    const ushort* __restrict__ A, long lda,
    const ushort* __restrict__ BT,
    const ushort* __restrict__ bias,
    ushort* __restrict__ Cb, float* __restrict__ Cf,
    long ldc, int K)
{
  __shared__ __align__(16) ushort As[128*32];
  __shared__ __align__(16) ushort Bs[128*32];
  const int tid = threadIdx.x;
  const int w = tid>>6, lane = tid&63, q = lane>>4, lr = lane&15;
  const int wm = (w>>1)*64, wn = (w&1)*64;
  const long mBase = (long)blockIdx.y*128, nBase = (long)blockIdx.x*128;

  f32x4 acc[4][4];
  #pragma unroll
  for(int i=0;i<4;i++)
    #pragma unroll
    for(int j=0;j<4;j++) acc[i][j]=(f32x4)(0.0f);

  const int idx0=tid, idx1=tid+256;
  const int ar0=idx0>>2, ac0=(idx0&3)*8;
  const int ar1=idx1>>2, ac1=(idx1&3)*8;

  const ushort* gA0 = A  + (mBase+ar0)*lda     + ac0;
  const ushort* gA1 = A  + (mBase+ar1)*lda     + ac1;
  const ushort* gB0 = BT + (nBase+ar0)*(long)K + ac0;
  const ushort* gB1 = BT + (nBase+ar1)*(long)K + ac1;
  ushort* lA0 = As + idx0*8;   // = LDS byte offset idx0*16: wave-uniform base + lane*16
  ushort* lA1 = As + idx1*8;
  ushort* lB0 = Bs + idx0*8;
  ushort* lB1 = Bs + idx1*8;

  for(int k0=0;k0<K;k0+=32){
    __syncthreads();                 // prev iter's ds_reads done before overwrite
    gl16(lA0, gA0 + k0);
    gl16(lA1, gA1 + k0);
    gl16(lB0, gB0 + k0);
    gl16(lB1, gB1 + k0);
    __syncthreads();                 // compiler emits vmcnt(0) drain -> LDS valid
    short8 af[4], bfr[4];
    #pragma unroll
    for(int mt=0;mt<4;mt++) af[mt]=*reinterpret_cast<const short8*>(As + (wm+mt*16+lr)*32 + q*8);
    #pragma unroll
    for(int nt=0;nt<4;nt++) bfr[nt]=*reinterpret_cast<const short8*>(Bs + (wn+nt*16+lr)*32 + q*8);
    #pragma unroll
    for(int mt=0;mt<4;mt++)
      #pragma unroll
      for(int nt=0;nt<4;nt++)
        acc[mt][nt]=__builtin_amdgcn_mfma_f32_16x16x32_bf16(af[mt],bfr[nt],acc[mt][nt],0,0,0);
  }

  #pragma unroll
  for(int nt=0;nt<4;nt++){
    long n = nBase+wn+nt*16+lr;
    float bv = bf2f(bias[n]);
    #pragma unroll
    for(int mt=0;mt<4;mt++){
      #pragma unroll
      for(int r=0;r<4;r++){
        long m = mBase+wm+mt*16+q*4+r;
        float v = acc[mt][nt][r]+bv;
        if constexpr (EPI==0){
          Cb[m*ldc+n]=f2bf(v);
        } else if constexpr (EPI==1){
          Cf[m*ldc+n]+=v;
        } else if constexpr (EPI==2){
          float partner = __shfl_xor(v,1);
          if(!(lane&1)) Cb[m*ldc + (n>>1)] = f2bf(gelu_exact(v)*partner);
        } else {
          long bl = m/65;
          int p = (int)(m - bl*65) - 1;
          if(p>=0 && n<72) Cf[bl*4608 + (long)p*72 + n] = v;
        }
      }
    }
  }
}

// ---------------- fused attention per (b,h): MFMA QK^T + softmax + MFMA PV ----------------
// Q,K natural [s][64] bf16 in LDS (A-frag / BT-frag layouts match gemm_bt's m89-verified
// mapping: row=lane&15, k=(lane>>4)*8). V staged transposed Vt[d][s] for the PV B-operand.
// Pad 65->80 rows (5 M/N tiles); PV K padded to 96 (3 k-steps) with P/Vt pad cols zeroed.
// LDS strides 72/81/104 break the 128B-row bank conflict (G4).
// r11: softmax wave-parallelized — one row per 4-lane group, shfl_xor(1,2) reduce.
__global__ __launch_bounds__(256) void attn_kernel(const ushort* __restrict__ qkv,
                                                   const float* __restrict__ rel_bias,
                                                   ushort* __restrict__ ctx, int layer)
{
  int bh = blockIdx.x;
  long b = bh>>3;
  int h = bh&7;
  __shared__ __align__(16) ushort Qb[80*72];    // 11520 B
  __shared__ __align__(16) ushort Kb[80*72];    // 11520 B
  __shared__ __align__(16) ushort Vt[64*104];   // 13312 B  Vt[d][s]
  __shared__ __align__(16) float  S [80*81];    // 25920 B
  __shared__ __align__(16) ushort Pb[80*104];   // 16640 B
  __shared__ float relb[225];
  const long tokBase = b*SEQ;
  const int tid = threadIdx.x;
  const int w = tid>>6, lane = tid&63, q = lane>>4, lr = lane&15;

  // ---- stage Q,K,V (V transposed), zero Vt pad cols, load bias table ----
  for(int idx=tid; idx<SEQ*8; idx+=256){           // 520 rows-of-8
    int s = idx>>3, c8 = (idx&7)<<3;
    long base = (tokBase+s)*1536 + h*64 + c8;
    *reinterpret_cast<short8*>(&Qb[s*72 + c8]) = *reinterpret_cast<const short8*>(&qkv[base]);
    *reinterpret_cast<short8*>(&Kb[s*72 + c8]) = *reinterpret_cast<const short8*>(&qkv[base+512]);
    short8 v = *reinterpret_cast<const short8*>(&qkv[base+1024]);
    #pragma unroll
    for(int j=0;j<8;j++) Vt[(c8+j)*104 + s] = (ushort)v[j];
  }
  for(int idx=tid; idx<64*32; idx+=256){           // zero Vt[d][65..96]
    int d = idx>>5, s = 65+(idx&31);
    Vt[d*104 + s] = 0;
  }
  if(tid<225) relb[tid] = rel_bias[((long)layer*225 + tid)*8 + h];
  __syncthreads();

  // ---- scores: S[qi][ki] = (Q @ K^T) * 0.125  via 5x5 tiles of 16x16x32 ----
  for(int tt=w; tt<25; tt+=4){
    int mt = tt/5, nt = tt - mt*5;
    f32x4 acc = (f32x4)(0.0f);
    #pragma unroll
    for(int ks=0;ks<2;ks++){
      short8 af = *reinterpret_cast<const short8*>(&Qb[(mt*16+lr)*72 + ks*32 + q*8]);
      short8 bf = *reinterpret_cast<const short8*>(&Kb[(nt*16+lr)*72 + ks*32 + q*8]);
      acc = __builtin_amdgcn_mfma_f32_16x16x32_bf16(af, bf, acc, 0,0,0);
    }
    int col = nt*16 + lr;
    #pragma unroll
    for(int r=0;r<4;r++)
      S[(mt*16 + q*4 + r)*81 + col] = acc[r]*0.125f;
  }
  __syncthreads();

  // ---- softmax per row: one row per 4-lane group (adds rel-pos bias) -> Pb bf16 ----
  {
    int grp = tid>>2, sub = tid&3;
    for(int qi=grp; qi<SEQ; qi+=64){
      float* srow = S + qi*81;
      int pq = qi-1;
      float mx = -1e30f;
      for(int k=sub;k<SEQ;k+=4){
        float s = srow[k];
        if(qi>0 && k>0){
          int pk = k-1;
          int ridx = (pq>>3)-(pk>>3)+7, fidx = (pq&7)-(pk&7)+7;
          s += relb[ridx*15+fidx];
        }
        srow[k] = s;
        mx = fmaxf(mx, s);
      }
      mx = fmaxf(mx, __shfl_xor(mx,1));
      mx = fmaxf(mx, __shfl_xor(mx,2));
      float sum = 0.f;
      for(int k=sub;k<SEQ;k+=4){ float e = __expf(srow[k]-mx); srow[k]=e; sum+=e; }
      sum += __shfl_xor(sum,1);
      sum += __shfl_xor(sum,2);
      float inv = 1.0f/sum;
      ushort* prow = Pb + qi*104;
      for(int k=sub;k<SEQ;k+=4) prow[k] = f2bf(srow[k]*inv);
      for(int k=SEQ+sub;k<96;k+=4) prow[k] = 0;    // zero pad -> PV k-steps safe
    }
  }
  __syncthreads();

  // ---- PV: ctx[qi][d] = P @ V  via 5x4 tiles, K=96 (3 k-steps) ----
  for(int tt=w; tt<20; tt+=4){
    int mt = tt>>2, nt = tt&3;
    f32x4 acc = (f32x4)(0.0f);
    #pragma unroll
    for(int ks=0;ks<3;ks++){
      short8 af = *reinterpret_cast<const short8*>(&Pb[(mt*16+lr)*104 + ks*32 + q*8]);
      short8 bf = *reinterpret_cast<const short8*>(&Vt[(nt*16+lr)*104 + ks*32 + q*8]);
      acc = __builtin_amdgcn_mfma_f32_16x16x32_bf16(af, bf, acc, 0,0,0);
    }
    int col = nt*16 + lr;
    #pragma unroll
    for(int r=0;r<4;r++){
      int row = mt*16 + q*4 + r;
      if(row < SEQ)
        ctx[(tokBase+row)*512 + h*64 + col] = f2bf(acc[r]);
    }
  }
}

// ---------------- value head MLP on CLS token (float out) ----------------
__global__ __launch_bounds__(256) void value_kernel(const ushort* __restrict__ h,
                                                    const float* __restrict__ v1_W, const float* __restrict__ v1_b,
                                                    const float* __restrict__ v2_W, const float* __restrict__ v2_b,
                                                    const float* __restrict__ v3_W, const float* __restrict__ v3_b,
                                                    float* __restrict__ out, long b0)
{
  long bl = blockIdx.x;
  int tid = threadIdx.x;
  __shared__ float vh[512], a1[256], a2[128];
  const ushort* hrow = h + bl*SEQ*DMODEL;   // CLS token
  for(int d=tid; d<512; d+=256) vh[d]=bf2f(hrow[d]);
  __syncthreads();
  {
    float acc = v1_b[tid];
    for(int k=0;k<512;k++) acc += vh[k]*v1_W[k*256+tid];
    a1[tid]=gelu_exact(acc);
  }
  __syncthreads();
  if(tid<128){
    float acc = v2_b[tid];
    for(int k=0;k<256;k++) acc += a1[k]*v2_W[k*128+tid];
    a2[tid]=gelu_exact(acc);
  }
  __syncthreads();
  if(tid==0){
    float acc = v3_b[0];
    for(int k=0;k<128;k++) acc += a2[k]*v3_W[k];
    out[(long)BATCH*4608 + b0 + bl] = tanhf(acc);
  }
}

extern "C" void kernel_launch(void* const* d_in, const int* in_sizes, int n_in,
                              void* d_out, int out_size, void* d_ws, size_t ws_size,
                              hipStream_t stream)
{
  const float* x        = (const float*)d_in[0];
  const float* emb_W    = (const float*)d_in[1];
  const float* emb_b    = (const float*)d_in[2];
  const float* cls      = (const float*)d_in[3];
  const float* abs_pos  = (const float*)d_in[4];
  const float* file_tab = (const float*)d_in[5];
  const float* rank_tab = (const float*)d_in[6];
  const float* diag_tab = (const float*)d_in[7];
  const float* anti_tab = (const float*)d_in[8];
  const float* rel_bias = (const float*)d_in[9];
  const float* Wq  = (const float*)d_in[10];
  const float* bq  = (const float*)d_in[11];
  const float* Wk  = (const float*)d_in[12];
  const float* bk  = (const float*)d_in[13];
  const float* Wv  = (const float*)d_in[14];
  const float* bv  = (const float*)d_in[15];
  const float* Wo  = (const float*)d_in[16];
  const float* bo  = (const float*)d_in[17];
  const float* ln1_g = (const float*)d_in[18];
  const float* ln1_b = (const float*)d_in[19];
  const float* ln2_g = (const float*)d_in[20];
  const float* ln2_b = (const float*)d_in[21];
  const float* W1  = (const float*)d_in[22];
  const float* b1  = (const float*)d_in[23];
  const float* W2  = (const float*)d_in[24];
  const float* b2  = (const float*)d_in[25];
  const float* fln_g = (const float*)d_in[26];
  const float* fln_b = (const float*)d_in[27];
  const float* pol_W = (const float*)d_in[28];
  const float* pol_b = (const float*)d_in[29];
  const float* v1_W  = (const float*)d_in[30];
  const float* v1_b  = (const float*)d_in[31];
  const float* v2_W  = (const float*)d_in[32];
  const float* v2_b  = (const float*)d_in[33];
  const float* v3_W  = (const float*)d_in[34];
  const float* v3_b  = (const float*)d_in[35];
  float* out = (float*)d_out;

  // --- runtime chunk selection: pick largest chunk that fits ws_size ---
  int nchunk = 4;
  if(ws_size >= (size_t)477345792) nchunk = 1;
  else if(ws_size >= (size_t)272873472) nchunk = 2;
  const int bch = BATCH / nchunk;          // batches per chunk
  const long mch = (long)bch * SEQ;        // tokens per chunk (divisible by 128/4)

  char* ws = (char*)d_ws;
  float*  t    = (float*)ws;  ws += (size_t)mch*DMODEL*4;
  ushort* h    = (ushort*)ws; ws += (size_t)mch*DMODEL*2;   // also ctx
  ushort* buf1 = (ushort*)ws; ws += (size_t)mch*1536*2;     // qkv / geglu out
  ushort* wT   = (ushort*)ws; ws += (size_t)WT_TOTAL*2;
  (void)ws_size; (void)in_sizes; (void)n_in; (void)out_size;

  // --- one-time weight prep ---
  prep_qkv<<<(7864320+255)/256,256,0,stream>>>(Wq,Wk,Wv,wT);
  prep_wo <<<(2621440+255)/256,256,0,stream>>>(Wo,wT);
  prep_w1 <<<(15728640+255)/256,256,0,stream>>>(W1,wT);
  prep_w2 <<<(7864320+255)/256,256,0,stream>>>(W2,wT);
  prep_bias<<<(56320+255)/256,256,0,stream>>>(bq,bk,bv,bo,b1,b2,wT);
  prep_pol <<<(65664+255)/256,256,0,stream>>>(pol_W,pol_b,wT);

  // --- per-chunk full network ---
  const int gy = (int)(mch/128);           // GEMM grid rows
  const int lng = (int)(mch/4);            // LN grid (4 tokens/block)
  for(int c=0;c<nchunk;c++){
    long b0 = (long)c*bch;
    embed_kernel<<<(int)mch,64,0,stream>>>(x, emb_W, emb_b, cls, abs_pos,
                                      file_tab, rank_tab, diag_tab, anti_tab, t, b0*64*16);
    for(int l=0;l<NLAYER;l++){
      ln_kernel<<<lng,256,0,stream>>>(t, h, ln1_g, ln1_b, l*512);
      gemm_bt<0><<<dim3(12,gy),256,0,stream>>>(h, 512, wT+WT_QKV+(long)l*786432,
                                                wT+WT_BQKV+l*1536, buf1, nullptr, 1536, 512);
      attn_kernel<<<bch*NHEAD,256,0,stream>>>(buf1, rel_bias, h, l);   // ctx -> h
      gemm_bt<1><<<dim3(4,gy),256,0,stream>>>(h, 512, wT+WT_WO+(long)l*262144,
                                               wT+WT_BO+l*512, nullptr, t, 512, 512);
      ln_kernel<<<lng,256,0,stream>>>(t, h, ln2_g, ln2_b, l*512);
      gemm_bt<2><<<dim3(24,gy),256,0,stream>>>(h, 512, wT+WT_W1+(long)l*1572864,
                                                wT+WT_B1+l*3072, buf1, nullptr, 1536, 512);
      gemm_bt<1><<<dim3(4,gy),256,0,stream>>>(buf1, 1536, wT+WT_W2+(long)l*786432,
                                               wT+WT_B2+l*512, nullptr, t, 512, 1536);
    }
    ln_kernel<<<lng,256,0,stream>>>(t, h, fln_g, fln_b, 0);
    gemm_bt<3><<<dim3(1,gy),256,0,stream>>>(h, 512, wT+WT_POL,
                                            wT+WT_BPOL, nullptr, out + b0*4608, 0, 512);
    value_kernel<<<bch,256,0,stream>>>(h, v1_W, v1_b, v2_W, v2_b, v3_W, v3_b, out, b0);
  }
}